// Round 3
// baseline (2485.252 us; speedup 1.0000x reference)
//
#include <hip/hip_runtime.h>

// ---------------------------------------------------------------------------
// SelfMatchEncoder: additive self-attention + bidirectional GRU
// N=1000, B=8, D=256, H=128
// ---------------------------------------------------------------------------

#define N_ 1000
#define B_ 8
#define D_ 256
#define H_ 128
#define G3_ 384  // 3*H

typedef __attribute__((ext_vector_type(8))) short short8_t;
typedef __attribute__((ext_vector_type(4))) float f32x4;

__device__ __forceinline__ float tanh_fast(float x) {
  float e = __expf(2.f * x);
  return 1.f - 2.f / (e + 1.f);
}
__device__ __forceinline__ float sigmoid_fast(float x) {
  return 1.f / (1.f + __expf(-x));
}
__device__ __forceinline__ unsigned short f2bf(float f) {
  unsigned u = __float_as_uint(f);
  unsigned r = u + 0x7fffu + ((u >> 16) & 1u);
  return (unsigned short)(r >> 16);
}
__device__ __forceinline__ float bf2f(unsigned short b) {
  return __uint_as_float(((unsigned)b) << 16);
}

// ---------------------------------------------------------------------------
// K1: vp[n,b,h] = sum_d pin[n,b,d] * W0[h,d]; store row layout and transposed
// ---------------------------------------------------------------------------
__global__ void k_vp(const float* __restrict__ pin, const float* __restrict__ W0,
                     float* __restrict__ vpR, float* __restrict__ vpT) {
  int n = blockIdx.x;
  int tid = threadIdx.x;  // 256
  __shared__ float xs[B_][D_];
  for (int k = 0; k < 8; ++k) {
    int idx = k * 256 + tid;  // 2048
    xs[idx >> 8][idx & 255] = pin[(size_t)n * (B_ * D_) + idx];
  }
  __syncthreads();
  for (int k = 0; k < 4; ++k) {
    int o = k * 256 + tid;  // 1024 = 8b * 128h
    int b = o >> 7, h = o & 127;
    const float4* wr = (const float4*)(W0 + (size_t)h * D_);
    float acc = 0.f;
#pragma unroll 8
    for (int dq = 0; dq < 64; ++dq) {
      float4 w = wr[dq];
      acc += xs[b][dq * 4 + 0] * w.x + xs[b][dq * 4 + 1] * w.y +
             xs[b][dq * 4 + 2] * w.z + xs[b][dq * 4 + 3] * w.w;
    }
    vpR[((size_t)b * N_ + n) * H_ + h] = acc;
    vpT[((size_t)b * H_ + h) * N_ + n] = acc;
  }
}

// ---------------------------------------------------------------------------
// K2: S[b,i,j] = sum_h vs[h]*tanh(vp_i[h]+vp_j[h]); mask -> -1e30
// block: (i-tile of 8) x b ; 256 threads, lane = j within 256-tile
// ---------------------------------------------------------------------------
__global__ void k_scores(const float* __restrict__ vpR, const float* __restrict__ vpT,
                         const float* __restrict__ vs, const int* __restrict__ mask,
                         float* __restrict__ S) {
  int b = blockIdx.y;
  int i0 = blockIdx.x * 8;
  int tid = threadIdx.x;  // 256
  __shared__ float vpi[8][H_];
  __shared__ float vss[H_];
  __shared__ float vpj[32][256];
  for (int k = 0; k < 4; ++k) {
    int o = k * 256 + tid;  // 1024
    vpi[o >> 7][o & 127] = vpR[((size_t)b * N_ + i0 + (o >> 7)) * H_ + (o & 127)];
  }
  if (tid < H_) vss[tid] = vs[tid];

  for (int jt = 0; jt < 4; ++jt) {
    int j0 = jt * 256;
    int cnt = min(256, N_ - j0);
    float acc[8] = {0.f, 0.f, 0.f, 0.f, 0.f, 0.f, 0.f, 0.f};
    for (int hc = 0; hc < 4; ++hc) {
      __syncthreads();
      for (int hh = 0; hh < 32; ++hh)
        vpj[hh][tid] = (tid < cnt) ? vpT[((size_t)b * H_ + hc * 32 + hh) * N_ + j0 + tid] : 0.f;
      __syncthreads();
      if (tid < cnt) {
        for (int hh = 0; hh < 32; ++hh) {
          float vj = vpj[hh][tid];
          float vsh = vss[hc * 32 + hh];
#pragma unroll
          for (int i = 0; i < 8; ++i)
            acc[i] += vsh * tanh_fast(vpi[i][hc * 32 + hh] + vj);
        }
      }
    }
    if (tid < cnt) {
      int mj = mask[(size_t)(j0 + tid) * B_ + b];
#pragma unroll
      for (int i = 0; i < 8; ++i)
        S[((size_t)b * N_ + i0 + i) * N_ + j0 + tid] = mj ? -1e30f : acc[i];
    }
  }
}

// ---------------------------------------------------------------------------
// K3: per-row softmax stats (max, 1/sumexp)
// ---------------------------------------------------------------------------
__global__ void k_rowstats(const float* __restrict__ S, float* __restrict__ m_,
                           float* __restrict__ rl_) {
  int i = blockIdx.x, b = blockIdx.y;
  int lane = threadIdx.x;  // 64
  const float* row = S + ((size_t)b * N_ + i) * N_;
  float mx = -3.0e38f;
  for (int j = lane; j < N_; j += 64) mx = fmaxf(mx, row[j]);
  for (int off = 32; off; off >>= 1) mx = fmaxf(mx, __shfl_xor(mx, off));
  float s = 0.f;
  for (int j = lane; j < N_; j += 64) s += __expf(row[j] - mx);
  for (int off = 32; off; off >>= 1) s += __shfl_xor(s, off);
  if (lane == 0) {
    m_[b * N_ + i] = mx;
    rl_[b * N_ + i] = 1.f / s;
  }
}

// ---------------------------------------------------------------------------
// K4: att[i,b,:] = sum_j P[i,j]*pin[j,b,:]; writes rnn_in = [att | pin]
// block: (i-tile of 16) x b ; 256 threads, lane = d
// ---------------------------------------------------------------------------
__global__ void k_pv(const float* __restrict__ S, const float* __restrict__ m_,
                     const float* __restrict__ rl_, const float* __restrict__ pin,
                     float* __restrict__ rnn) {
  int b = blockIdx.y;
  int i0 = blockIdx.x * 16;
  int ni = min(16, N_ - i0);
  int tid = threadIdx.x;  // 256
  __shared__ float ps[32][256];
  __shared__ float Ps[16][32];
  __shared__ float mi[16], ri[16];
  if (tid < 16) {
    int ii = i0 + tid;
    mi[tid] = (ii < N_) ? m_[b * N_ + ii] : 0.f;
    ri[tid] = (ii < N_) ? rl_[b * N_ + ii] : 0.f;
  }
  float acc[16];
#pragma unroll
  for (int i = 0; i < 16; ++i) acc[i] = 0.f;

  for (int jc = 0; jc < 32; ++jc) {  // 1000 = 31*32 + 8
    int j0 = jc * 32;
    int cj = min(32, N_ - j0);
    __syncthreads();
    for (int jj = 0; jj < cj; ++jj)
      ps[jj][tid] = pin[((size_t)(j0 + jj) * B_ + b) * D_ + tid];
#pragma unroll
    for (int k = 0; k < 2; ++k) {
      int v = k * 256 + tid;  // 512 = 16*32
      int il = v >> 5, jj = v & 31;
      float p = 0.f;
      if (il < ni && jj < cj)
        p = __expf(S[((size_t)b * N_ + i0 + il) * N_ + j0 + jj] - mi[il]) * ri[il];
      Ps[il][jj] = p;
    }
    __syncthreads();
    for (int jj = 0; jj < 32; ++jj) {
      float pv = ps[jj][tid];
#pragma unroll
      for (int i = 0; i < 16; ++i) acc[i] += Ps[i][jj] * pv;
    }
  }
  for (int i = 0; i < ni; ++i) {
    size_t base = ((size_t)(i0 + i) * B_ + b) * (2 * D_);
    rnn[base + tid] = acc[i];
    rnn[base + D_ + tid] = pin[((size_t)(i0 + i) * B_ + b) * D_ + tid];
  }
}

// ---------------------------------------------------------------------------
// K5: xw[n,b,g] = bias[g] + sum_k rnn[n,b,k]*W_ih[g,k]   (both directions)
// block: n x dir ; 256 threads; 8-way b register blocking
// ---------------------------------------------------------------------------
__global__ void k_xw(const float* __restrict__ rnn, const float* __restrict__ Wf,
                     const float* __restrict__ bf, const float* __restrict__ Wb,
                     const float* __restrict__ bb, float* __restrict__ xwf,
                     float* __restrict__ xwb) {
  int n = blockIdx.x;
  int dir = blockIdx.y;
  const float* W = dir ? Wb : Wf;
  const float* bias = dir ? bb : bf;
  float* xw = dir ? xwb : xwf;
  int tid = threadIdx.x;  // 256
  __shared__ float xs[B_][2 * D_];
  for (int k = 0; k < 16; ++k) {
    int o = k * 256 + tid;  // 4096
    xs[o >> 9][o & 511] = rnn[(size_t)n * (B_ * 2 * D_) + o];
  }
  __syncthreads();
  for (int gk = 0; gk < 2; ++gk) {
    int g = gk * 256 + tid;
    if (g < G3_) {
      float acc[8];
      float bv = bias[g];
#pragma unroll
      for (int b = 0; b < 8; ++b) acc[b] = bv;
      const float4* wr = (const float4*)(W + (size_t)g * (2 * D_));
      for (int kq = 0; kq < 128; ++kq) {
        float4 w = wr[kq];
#pragma unroll
        for (int b = 0; b < 8; ++b) {
          float4 x = *(const float4*)&xs[b][kq * 4];
          acc[b] += x.x * w.x + x.y * w.y + x.z * w.z + x.w * w.w;
        }
      }
#pragma unroll
      for (int b = 0; b < 8; ++b)
        xw[((size_t)n * B_ + b) * G3_ + g] = acc[b];
    }
  }
}

// ---------------------------------------------------------------------------
// K6: GRU scan. 2 blocks (dir), 512 threads (8 waves).
// hw = h @ W_hh^T via mfma_f32_16x16x32_bf16 with hi/lo split (fp32 accuracy).
// W fragments live in registers; h in LDS as bf16 hi/lo; gates fp32.
// ---------------------------------------------------------------------------
#define HPAD 136

__global__ __launch_bounds__(512) void k_gru(const float* __restrict__ xwf,
                                             const float* __restrict__ xwb,
                                             const float* __restrict__ Whf,
                                             const float* __restrict__ Whb,
                                             const float* __restrict__ bhf,
                                             const float* __restrict__ bhb,
                                             float* __restrict__ out) {
  int dir = blockIdx.x;
  const float* xw = dir ? xwb : xwf;
  const float* Wh = dir ? Whb : Whf;
  const float* bh = dir ? bhb : bhf;

  __shared__ unsigned short hhi[16][HPAD];
  __shared__ unsigned short hlo[16][HPAD];
  __shared__ float hw[B_][G3_];
  __shared__ float hprev[B_][H_];
  __shared__ float bhs[G3_];

  int tid = threadIdx.x;
  int w = tid >> 6;    // wave 0..7
  int lane = tid & 63;
  int col = lane & 15;  // N-index within tile (g), also A row (b)
  int krow = lane >> 4; // 0..3 -> k-offset selector

  for (int k = tid; k < 16 * HPAD; k += 512) {
    ((unsigned short*)hhi)[k] = 0;
    ((unsigned short*)hlo)[k] = 0;
  }
  for (int k = tid; k < B_ * H_; k += 512) ((float*)hprev)[k] = 0.f;
  if (tid < G3_) bhs[tid] = bh[tid];

  // Load W_hh fragments: wave w owns g-tiles 3w..3w+2 (24 tiles of 16 g).
  // B-frag (tile t, kchunk kc): lane holds W[g0+col][kc*32 + krow*8 + j], j=0..7
  short8_t bhi_f[3][4], blo_f[3][4];
#pragma unroll
  for (int t = 0; t < 3; ++t) {
    int g = (w * 3 + t) * 16 + col;
#pragma unroll
    for (int kc = 0; kc < 4; ++kc) {
      int c = kc * 32 + krow * 8;
      const float* wp = Wh + (size_t)g * H_ + c;
      short8_t hi8, lo8;
#pragma unroll
      for (int j = 0; j < 8; ++j) {
        float v = wp[j];
        unsigned short h = f2bf(v);
        float rem = v - bf2f(h);
        hi8[j] = (short)h;
        lo8[j] = (short)f2bf(rem);
      }
      bhi_f[t][kc] = hi8;
      blo_f[t][kc] = lo8;
    }
  }
  __syncthreads();

  float xcur[6], xnxt[6];
#define LOADXW(T, DST)                                          \
  do {                                                          \
    int _t = (T);                                               \
    if (_t < N_) {                                              \
      int _n = dir ? (N_ - 1 - _t) : _t;                        \
      _Pragma("unroll") for (int k = 0; k < 2; ++k) {           \
        int o = k * 512 + tid;                                  \
        int b = o >> 7, c = o & 127;                            \
        size_t xb = ((size_t)_n * B_ + b) * G3_ + c;            \
        DST[k * 3 + 0] = xw[xb];                                \
        DST[k * 3 + 1] = xw[xb + 128];                          \
        DST[k * 3 + 2] = xw[xb + 256];                          \
      }                                                         \
    }                                                           \
  } while (0)

  LOADXW(0, xcur);

  for (int t = 0; t < N_; ++t) {
    int n = dir ? (N_ - 1 - t) : t;
    LOADXW(t + 1, xnxt);  // prefetch next step early

    // ---- Phase A: hw = h @ W_hh^T (hi/lo split MFMA) ----
    short8_t ahi[4], alo[4];
#pragma unroll
    for (int kc = 0; kc < 4; ++kc) {
      int c = kc * 32 + krow * 8;
      ahi[kc] = *(const short8_t*)&hhi[col][c];
      alo[kc] = *(const short8_t*)&hlo[col][c];
    }
#pragma unroll
    for (int tt = 0; tt < 3; ++tt) {
      f32x4 acc = {0.f, 0.f, 0.f, 0.f};
#pragma unroll
      for (int kc = 0; kc < 4; ++kc) {
        acc = __builtin_amdgcn_mfma_f32_16x16x32_bf16(ahi[kc], bhi_f[tt][kc], acc, 0, 0, 0);
        acc = __builtin_amdgcn_mfma_f32_16x16x32_bf16(alo[kc], bhi_f[tt][kc], acc, 0, 0, 0);
        acc = __builtin_amdgcn_mfma_f32_16x16x32_bf16(ahi[kc], blo_f[tt][kc], acc, 0, 0, 0);
      }
      int gbase = (w * 3 + tt) * 16 + col;
#pragma unroll
      for (int i = 0; i < 4; ++i) {
        int b = krow * 4 + i;  // C/D row = (lane>>4)*4 + reg
        if (b < B_) hw[b][gbase] = acc[i];
      }
    }
    __syncthreads();

    // ---- Phase B: gates + h update (1024 outputs, 2/thread) ----
#pragma unroll
    for (int k = 0; k < 2; ++k) {
      int o = k * 512 + tid;
      int b = o >> 7, c = o & 127;
      float xr = xcur[k * 3 + 0], xz = xcur[k * 3 + 1], xn = xcur[k * 3 + 2];
      float hr = hw[b][c] + bhs[c];
      float hz = hw[b][128 + c] + bhs[128 + c];
      float hn = hw[b][256 + c] + bhs[256 + c];
      float r = sigmoid_fast(xr + hr);
      float z = sigmoid_fast(xz + hz);
      float nn = tanh_fast(xn + r * hn);
      float hp = hprev[b][c];
      float h2 = (1.f - z) * nn + z * hp;
      hprev[b][c] = h2;
      unsigned short hi = f2bf(h2);
      hhi[b][c] = hi;
      hlo[b][c] = f2bf(h2 - bf2f(hi));
      out[((size_t)n * B_ + b) * (2 * H_) + dir * H_ + c] = h2;
    }
    __syncthreads();
#pragma unroll
    for (int q = 0; q < 6; ++q) xcur[q] = xnxt[q];
  }
#undef LOADXW
}

// ---------------------------------------------------------------------------
extern "C" void kernel_launch(void* const* d_in, const int* in_sizes, int n_in,
                              void* d_out, int out_size, void* d_ws, size_t ws_size,
                              hipStream_t stream) {
  const float* pin  = (const float*)d_in[0];
  const int*   mask = (const int*)d_in[1];
  const float* W0   = (const float*)d_in[2];
  const float* vs   = (const float*)d_in[3];
  const float* Wihf = (const float*)d_in[4];
  const float* Whhf = (const float*)d_in[5];
  const float* bihf = (const float*)d_in[6];
  const float* bhhf = (const float*)d_in[7];
  const float* Wihb = (const float*)d_in[8];
  const float* Whhb = (const float*)d_in[9];
  const float* bihb = (const float*)d_in[10];
  const float* bhhb = (const float*)d_in[11];
  float* out = (float*)d_out;
  float* ws = (float*)d_ws;

  float* vpR = ws;                  // 1,024,000
  float* vpT = ws + 1024000;        // 1,024,000
  float* S   = ws + 2048000;        // 8,000,000
  float* m_  = ws + 10048000;       // 8,000
  float* rl_ = ws + 10056000;       // 8,000
  float* rnn = ws + 10064000;       // 4,096,000
  float* xwf = ws + 14160000;       // 3,072,000
  float* xwb = ws + 17232000;       // 3,072,000

  hipLaunchKernelGGL(k_vp, dim3(N_), dim3(256), 0, stream, pin, W0, vpR, vpT);
  hipLaunchKernelGGL(k_scores, dim3(125, 8), dim3(256), 0, stream, vpR, vpT, vs, mask, S);
  hipLaunchKernelGGL(k_rowstats, dim3(N_, 8), dim3(64), 0, stream, S, m_, rl_);
  hipLaunchKernelGGL(k_pv, dim3(63, 8), dim3(256), 0, stream, S, m_, rl_, pin, rnn);
  hipLaunchKernelGGL(k_xw, dim3(N_, 2), dim3(256), 0, stream, rnn, Wihf, bihf, Wihb, bihb, xwf, xwb);
  hipLaunchKernelGGL(k_gru, dim3(2), dim3(512), 0, stream, xwf, xwb, Whhf, Whhb, bhhf, bhhb, out);
}